// Round 5
// baseline (100.344 us; speedup 1.0000x reference)
//
#include <hip/hip_runtime.h>
#include <hip/hip_bf16.h>

// EnhancedBCMLayer: block-circulant matmul == dense GEMM
//   out = X (4096x2048) @ W^T (2048x2048) + b, fp32 out
//   W[f*16+t][g*16+u] = iv[f, g, (t-u)&15]
// GEMM: BM=256 x BN=128 x BK=64, grid 256 (1 block/CU), 8 waves.
// Split-K in block: 4 tile-waves (2Mx2N, per-wave 128x64) x 2 K-groups;
// mfma_f32_32x32x16_bf16; 3-buffer LDS; 1 barrier + vmcnt(6) + lgkm(12)/tile;
// LDS pair-reduction epilogue. T1 XCD swizzle + T2 XOR swizzle + T5 setprio.

#define M_DIM 4096
#define N_DIM 2048
#define K_DIM 2048
#define BK 64
#define NT (K_DIM / BK)   // 32 K-tiles
#define BUFSZ 49152       // 48 KB: A [256][128B] + B [128][128B]

typedef __attribute__((ext_vector_type(8))) short bf16x8;
typedef __attribute__((ext_vector_type(4))) float f32x4;
typedef __attribute__((ext_vector_type(16))) float f32x16;

typedef const __attribute__((address_space(1))) void gvoid_t;
typedef __attribute__((address_space(3))) void lvoid_t;

#define FENCE asm volatile("" ::: "memory")
#define BAR()  do { FENCE; __builtin_amdgcn_s_barrier(); FENCE; } while (0)
#define GLD(src, dst) __builtin_amdgcn_global_load_lds((gvoid_t*)(src), (lvoid_t*)(dst), 16, 0, 0)

#define STAGE_A(dst, src) (GLD((src) + 0 * 64 * K_DIM, (dst) + 0),     \
                           GLD((src) + 1 * 64 * K_DIM, (dst) + 8192),  \
                           GLD((src) + 2 * 64 * K_DIM, (dst) + 16384), \
                           GLD((src) + 3 * 64 * K_DIM, (dst) + 24576))
#define STAGE_B(dst, src) (GLD((src) + 0 * 64 * K_DIM, (dst) + 0),     \
                           GLD((src) + 1 * 64 * K_DIM, (dst) + 8192))

// fp32 -> bf16 RNE
__device__ __forceinline__ unsigned int f2bf(float f) {
  unsigned int u = __float_as_uint(f);
  return (u + 0x7fffu + ((u >> 16) & 1u)) >> 16;
}

// ---------------- fused prologue: cvt X -> bf16  |  expand iv -> dense bf16 W [N][K] ----------------
__global__ __launch_bounds__(256) void prep_kernel(const float* __restrict__ x,
                                                   const float* __restrict__ iv,
                                                   unsigned short* __restrict__ xb,
                                                   unsigned short* __restrict__ W) {
  int b = blockIdx.x;
  if (b < (M_DIM * K_DIM / 8) / 256) {
    int idx = b * 256 + threadIdx.x;
    const float4* x4 = (const float4*)x;
    float4 a = x4[idx * 2 + 0];
    float4 c = x4[idx * 2 + 1];
    uint4 o;
    o.x = f2bf(a.x) | (f2bf(a.y) << 16);
    o.y = f2bf(a.z) | (f2bf(a.w) << 16);
    o.z = f2bf(c.x) | (f2bf(c.y) << 16);
    o.w = f2bf(c.z) | (f2bf(c.w) << 16);
    ((uint4*)xb)[idx] = o;
  } else {
    int idx = (b - (M_DIM * K_DIM / 8) / 256) * 256 + threadIdx.x;
    int o  = idx >> 8;
    int i0 = (idx & 255) * 8;
    int f = o >> 4, t = o & 15;
    int g = i0 >> 4, u0 = i0 & 15;
    const float* row = iv + (f * 128 + g) * 16;
    unsigned int p[4];
#pragma unroll
    for (int j = 0; j < 4; ++j) {
      unsigned int lo = f2bf(row[(t - (u0 + 2 * j + 0)) & 15]);
      unsigned int hi = f2bf(row[(t - (u0 + 2 * j + 1)) & 15]);
      p[j] = lo | (hi << 16);
    }
    ((uint4*)W)[idx] = make_uint4(p[0], p[1], p[2], p[3]);
  }
}

// ---------------- main GEMM ----------------
__global__ __launch_bounds__(512, 2) void gemm_bias_kernel(const unsigned short* __restrict__ A,
                                                           const unsigned short* __restrict__ B,
                                                           const float* __restrict__ bias,
                                                           float* __restrict__ C) {
  __shared__ char lds[3 * BUFSZ];   // 144 KB

  const int tid = threadIdx.x;
  const int l   = tid & 63;
  const int w   = tid >> 6;       // wave 0..7
  const int wm  = (w >> 1) & 1;   // tile-wave M (128 rows)
  const int wn  = w & 1;          // tile-wave N (64 cols)
  const int kg  = w >> 2;         // K-group 0/1

  // T1: XCD-aware bijective swizzle (grid=256)
  const int orig = blockIdx.x;
  const int swz  = (orig & 7) * 32 + (orig >> 3);
  const int bm   = swz >> 4;      // 0..15
  const int bn   = swz & 15;      // 0..15

  f32x16 acc[4][2] = {};          // [mm][nn]: 32x32 frags; rows wm*128+mm*32, cols wn*64+nn*32

  // ---- staging (identical machinery to verified rounds): linear LDS dest, inverse-swz source ----
  const int srow  = w * 8 + (l >> 3);
  const int sslot = (l & 7) ^ ((l >> 3) & 7);
  const unsigned short* Asrc0 = A + (size_t)(bm * 256 + srow) * K_DIM + sslot * 8;
  const unsigned short* Bsrc0 = B + (size_t)(bn * 128 + srow) * K_DIM + sslot * 8;

  // ---- ds_read frag addresses (T2 swizzled) ----
  // 32x32x16 A/B frag: row = l&31, k = (l>>5)*8 + 0..7  (16B per lane per frag)
  const int rxor = (l & 7) << 4;                         // (row&7)<<4, row&7 == l&7
  const int aRowB = (wm * 128 + (l & 31)) * 128;         // + mm*32*128
  const int bRowB = (wn * 64 + (l & 31)) * 128;          // + nn*32*128
  const int kc0 = (kg * 64 + 0 * 32 + (l >> 5) * 16) ^ rxor;  // substep 0
  const int kc1 = (kg * 64 + 1 * 32 + (l >> 5) * 16) ^ rxor;  // substep 1

  bf16x8 fa0[4][2], fb0[2][2], fa1[4][2], fb1[2][2];

#define LDFRAGS(FA, FB, BUFC)                                           \
  do {                                                                  \
    const char* Ab_ = lds + (BUFC) * BUFSZ;                             \
    const char* Bb_ = Ab_ + 32768;                                      \
    _Pragma("unroll")                                                   \
    for (int mm = 0; mm < 4; ++mm) {                                    \
      FA[mm][0] = *(const bf16x8*)(Ab_ + aRowB + mm * 4096 + kc0);      \
      FA[mm][1] = *(const bf16x8*)(Ab_ + aRowB + mm * 4096 + kc1);      \
    }                                                                   \
    _Pragma("unroll")                                                   \
    for (int nn = 0; nn < 2; ++nn) {                                    \
      FB[nn][0] = *(const bf16x8*)(Bb_ + bRowB + nn * 4096 + kc0);      \
      FB[nn][1] = *(const bf16x8*)(Bb_ + bRowB + nn * 4096 + kc1);      \
    }                                                                   \
  } while (0)

#define MFMA16(FA, FB, CNT)                                             \
  do {                                                                  \
    asm volatile("s_waitcnt lgkmcnt(" #CNT ")" ::: "memory");           \
    __builtin_amdgcn_sched_barrier(0);                                  \
    __builtin_amdgcn_s_setprio(1);                                      \
    _Pragma("unroll")                                                   \
    for (int s = 0; s < 2; ++s)                                         \
      _Pragma("unroll")                                                 \
      for (int mm = 0; mm < 4; ++mm)                                    \
        _Pragma("unroll")                                               \
        for (int nn = 0; nn < 2; ++nn)                                  \
          acc[mm][nn] = __builtin_amdgcn_mfma_f32_32x32x16_bf16(FA[mm][s], FB[nn][s], acc[mm][nn], 0, 0, 0); \
    __builtin_amdgcn_s_setprio(0);                                      \
    __builtin_amdgcn_sched_barrier(0);                                  \
  } while (0)

  // body t: stage t+2 -> buf (t+2)%3; vmcnt(6) (t+1 landed); BAR;
  //         read frags(t+1) from buf (t+1)%3; lgkm(12) (frags(t) ready); MFMA(t)
#define BODY(T, BUF2, BUF1, FAc, FBc, FAn, FBn)                         \
  do {                                                                  \
    STAGE_A(lds + (BUF2) * BUFSZ + w * 1024, Asrc0 + ((T) + 2) * BK);   \
    STAGE_B(lds + (BUF2) * BUFSZ + 32768 + w * 1024, Bsrc0 + ((T) + 2) * BK); \
    asm volatile("s_waitcnt vmcnt(6)" ::: "memory");                    \
    BAR();                                                              \
    LDFRAGS(FAn, FBn, BUF1);                                            \
    MFMA16(FAc, FBc, 12);                                               \
  } while (0)

  // ---- prologue: stage tiles 0,1; preload frags(0) ----
  STAGE_A(lds + 0 * BUFSZ + w * 1024, Asrc0 + 0 * BK);
  STAGE_B(lds + 0 * BUFSZ + 32768 + w * 1024, Bsrc0 + 0 * BK);
  STAGE_A(lds + 1 * BUFSZ + w * 1024, Asrc0 + 1 * BK);
  STAGE_B(lds + 1 * BUFSZ + 32768 + w * 1024, Bsrc0 + 1 * BK);
  asm volatile("s_waitcnt vmcnt(6)" ::: "memory");   // tile 0 landed
  BAR();
  LDFRAGS(fa0, fb0, 0);

  // ---- main loop: bodies 0..29, unroll x6 (LCM of buf%3 and set%2) ----
  for (int t = 0; t < NT - 2; t += 6) {
    BODY(t + 0, 2, 1, fa0, fb0, fa1, fb1);
    BODY(t + 1, 0, 2, fa1, fb1, fa0, fb0);
    BODY(t + 2, 1, 0, fa0, fb0, fa1, fb1);
    BODY(t + 3, 2, 1, fa1, fb1, fa0, fb0);
    BODY(t + 4, 0, 2, fa0, fb0, fa1, fb1);
    BODY(t + 5, 1, 0, fa1, fb1, fa0, fb0);
  }

  // ---- body 30: no stage; drain; read frags(31) from buf 1; MFMA(30) ----
  asm volatile("s_waitcnt vmcnt(0)" ::: "memory");
  BAR();
  LDFRAGS(fa1, fb1, 1);
  MFMA16(fa0, fb0, 12);
  // ---- body 31 ----
  MFMA16(fa1, fb1, 0);   // lgkm(0): all frag reads drained

  // ---- epilogue: split-K pair reduction through LDS ----
  // Pair p = w&3 (waves p and p+4 share the 128x64 output tile).
  // kg1 writes acc halves mm{0,1} to sub0; kg0 writes mm{2,3} to sub1.
  // Then kg0 reduces+stores rows mm{0,1}; kg1 reduces+stores mm{2,3}.
  // Region per pair: 2 subs x [64 cols][68 rows] col-major f32
  // (stride 68: quads 16B-aligned; bank advance 4/col -> 4-way, acceptable).
  BAR();   // all waves past MFMA; staging fully drained (vmcnt 0 above)
  {
    const int p = w & 3;
    float* rb = (float*)lds + (size_t)p * 2 * 64 * 68;
    float* mysub  = rb + (kg ? 0 : 1) * 64 * 68;   // where I WRITE (half I give away)
    float* othsub = rb + (kg ? 1 : 0) * 64 * 68;   // where I READ (partner's partial of my half)
    const int mmw0 = kg ? 0 : 2;                   // mm half I give away
    const int mmk0 = kg ? 2 : 0;                   // mm half I keep and store
#pragma unroll
    for (int mi = 0; mi < 2; ++mi)
#pragma unroll
      for (int nn = 0; nn < 2; ++nn)
#pragma unroll
        for (int q = 0; q < 4; ++q) {
          const int rloc = mi * 32 + q * 8 + (l >> 5) * 4;
          const int col  = nn * 32 + (l & 31);
          f32x4 v;
          v[0] = acc[mmw0 + mi][nn][q * 4 + 0];
          v[1] = acc[mmw0 + mi][nn][q * 4 + 1];
          v[2] = acc[mmw0 + mi][nn][q * 4 + 2];
          v[3] = acc[mmw0 + mi][nn][q * 4 + 3];
          *(f32x4*)(mysub + col * 68 + rloc) = v;
        }
    asm volatile("s_waitcnt lgkmcnt(0)" ::: "memory");
    BAR();
    const int col0 = bn * 128 + wn * 64;
#pragma unroll
    for (int nn = 0; nn < 2; ++nn) {
      const float bv = bias[col0 + nn * 32 + (l & 31)];
#pragma unroll
      for (int mi = 0; mi < 2; ++mi) {
#pragma unroll
        for (int q = 0; q < 4; ++q) {
          const int rloc = mi * 32 + q * 8 + (l >> 5) * 4;
          const int col  = nn * 32 + (l & 31);
          f32x4 r = *(const f32x4*)(othsub + col * 68 + rloc);
          const int crow = bm * 256 + wm * 128 + (mmk0 + mi) * 32 + q * 8 + (l >> 5) * 4;
          const int ccol = col0 + nn * 32 + (l & 31);
#pragma unroll
          for (int j = 0; j < 4; ++j) {
            C[(size_t)(crow + j) * N_DIM + ccol] =
                acc[mmk0 + mi][nn][q * 4 + j] + r[j] + bv;
          }
        }
      }
    }
  }
#undef BODY
#undef MFMA16
#undef LDFRAGS
}

// ---------------- fallback (ws too small): direct fp32 ----------------
__global__ __launch_bounds__(256) void fallback_kernel(const float* __restrict__ x,
                                                       const float* __restrict__ iv,
                                                       const float* __restrict__ b,
                                                       float* __restrict__ out) {
  int idx = blockIdx.x * 256 + threadIdx.x;
  int Bn = idx >> 11, o = idx & 2047;
  int f = o >> 4, t = o & 15;
  const float* xr = x + (size_t)Bn * 2048;
  float acc = 0.f;
  for (int g = 0; g < 128; ++g) {
    const float* pr = iv + (f * 128 + g) * 16;
    const float* xg = xr + g * 16;
#pragma unroll
    for (int s = 0; s < 16; ++s) acc += pr[s] * xg[(t - s) & 15];
  }
  out[idx] = acc + b[o];
}

extern "C" void kernel_launch(void* const* d_in, const int* in_sizes, int n_in,
                              void* d_out, int out_size, void* d_ws, size_t ws_size,
                              hipStream_t stream) {
  const float* x    = (const float*)d_in[0];
  const float* iv   = (const float*)d_in[1];
  const float* bias = (const float*)d_in[2];
  float* out = (float*)d_out;

  const size_t xb_bytes = (size_t)M_DIM * K_DIM * 2;
  const size_t w_bytes  = (size_t)N_DIM * K_DIM * 2;
  if (ws_size < xb_bytes + w_bytes) {
    fallback_kernel<<<(M_DIM * N_DIM) / 256, 256, 0, stream>>>(x, iv, bias, out);
    return;
  }

  unsigned short* xb = (unsigned short*)d_ws;
  unsigned short* W  = xb + (size_t)M_DIM * K_DIM;

  const int cvt_blocks = (M_DIM * K_DIM / 8) / 256;   // 4096
  const int bw_blocks  = (N_DIM * K_DIM / 8) / 256;   // 2048
  prep_kernel<<<cvt_blocks + bw_blocks, 256, 0, stream>>>(x, iv, xb, W);

  gemm_bias_kernel<<<(M_DIM / 256) * (N_DIM / 128), 512, 0, stream>>>(xb, W, bias, out);
}

// Round 6
// 99.923 us; speedup vs baseline: 1.0042x; 1.0042x over previous
//
#include <hip/hip_runtime.h>
#include <hip/hip_bf16.h>

// EnhancedBCMLayer: block-circulant matmul == dense GEMM
//   out = X (4096x2048) @ W^T (2048x2048) + b, fp32 out
//   W[f*16+t][g*16+u] = iv[f, g, (t-u)&15]
// GEMM: BM=256 x BN=128 x BK=64, grid 256 (1 block/CU), 8 waves (4M x 2N),
// per-wave 64x64, mfma_f32_16x16x32_bf16.
// A: global_load_lds staged, 3 LDS buffers, T2 XOR swizzle.
// B: fragments loaded DIRECTLY global->VGPR (W is L1/L2-resident; halves LDS
//    traffic -> MFMA-bound). Ping-pong frag sets, 1 barrier/tile,
//    vmcnt(8) top-of-body, lgkm(8) before MFMA. T1 XCD swizzle + T5 setprio.

#define M_DIM 4096
#define N_DIM 2048
#define K_DIM 2048
#define BK 64
#define NT (K_DIM / BK)   // 32 K-tiles
#define ABUF 32768        // 32 KB per A buffer [256 rows][128 B]

typedef __attribute__((ext_vector_type(8))) short bf16x8;
typedef __attribute__((ext_vector_type(4))) float f32x4;

typedef const __attribute__((address_space(1))) void gvoid_t;
typedef __attribute__((address_space(3))) void lvoid_t;

#define FENCE asm volatile("" ::: "memory")
#define BAR()  do { FENCE; __builtin_amdgcn_s_barrier(); FENCE; } while (0)
#define GLD(src, dst) __builtin_amdgcn_global_load_lds((gvoid_t*)(src), (lvoid_t*)(dst), 16, 0, 0)

// A staging: 4 GLDs cover 256 rows x 64 k (tile t at Asrc0 + t*BK)
#define STAGE_A(dst, src) (GLD((src) + 0 * 64 * K_DIM, (dst) + 0),     \
                           GLD((src) + 1 * 64 * K_DIM, (dst) + 8192),  \
                           GLD((src) + 2 * 64 * K_DIM, (dst) + 16384), \
                           GLD((src) + 3 * 64 * K_DIM, (dst) + 24576))

// fp32 -> bf16 RNE
__device__ __forceinline__ unsigned int f2bf(float f) {
  unsigned int u = __float_as_uint(f);
  return (u + 0x7fffu + ((u >> 16) & 1u)) >> 16;
}

// ---------------- fused prologue: cvt X -> bf16  |  expand iv -> dense bf16 W [N][K] ----------------
__global__ __launch_bounds__(256) void prep_kernel(const float* __restrict__ x,
                                                   const float* __restrict__ iv,
                                                   unsigned short* __restrict__ xb,
                                                   unsigned short* __restrict__ W) {
  int b = blockIdx.x;
  if (b < (M_DIM * K_DIM / 8) / 256) {
    int idx = b * 256 + threadIdx.x;
    const float4* x4 = (const float4*)x;
    float4 a = x4[idx * 2 + 0];
    float4 c = x4[idx * 2 + 1];
    uint4 o;
    o.x = f2bf(a.x) | (f2bf(a.y) << 16);
    o.y = f2bf(a.z) | (f2bf(a.w) << 16);
    o.z = f2bf(c.x) | (f2bf(c.y) << 16);
    o.w = f2bf(c.z) | (f2bf(c.w) << 16);
    ((uint4*)xb)[idx] = o;
  } else {
    int idx = (b - (M_DIM * K_DIM / 8) / 256) * 256 + threadIdx.x;
    int o  = idx >> 8;
    int i0 = (idx & 255) * 8;
    int f = o >> 4, t = o & 15;
    int g = i0 >> 4, u0 = i0 & 15;
    const float* row = iv + (f * 128 + g) * 16;
    unsigned int p[4];
#pragma unroll
    for (int j = 0; j < 4; ++j) {
      unsigned int lo = f2bf(row[(t - (u0 + 2 * j + 0)) & 15]);
      unsigned int hi = f2bf(row[(t - (u0 + 2 * j + 1)) & 15]);
      p[j] = lo | (hi << 16);
    }
    ((uint4*)W)[idx] = make_uint4(p[0], p[1], p[2], p[3]);
  }
}

// ---------------- main GEMM ----------------
__global__ __launch_bounds__(512, 2) void gemm_bias_kernel(const unsigned short* __restrict__ A,
                                                           const unsigned short* __restrict__ B,
                                                           const float* __restrict__ bias,
                                                           float* __restrict__ C) {
  __shared__ char lds[3 * ABUF];   // 96 KB, A tiles only

  const int tid = threadIdx.x;
  const int l   = tid & 63;
  const int w   = tid >> 6;       // wave 0..7
  const int wm  = w >> 1;         // wave M 0..3 (64 rows each)
  const int wn  = w & 1;          // wave N 0..1 (64 cols each)

  // T1: XCD-aware bijective swizzle (grid=256, 256%8==0)
  const int orig = blockIdx.x;
  const int swz  = (orig & 7) * 32 + (orig >> 3);
  const int bm   = swz >> 4;      // 0..15
  const int bn   = swz & 15;      // 0..15

  f32x4 acc[4][4] = {};

  // ---- A staging addresses (linear LDS dest, inverse-swizzled global source) ----
  const int srow  = w * 8 + (l >> 3);
  const int sslot = (l & 7) ^ ((l >> 3) & 7);
  const unsigned short* Asrc0 = A + (size_t)(bm * 256 + srow) * K_DIM + sslot * 8;

  // ---- A ds_read frag addresses (T2 swizzled) ----
  const int fr = l & 15;
  const int rxor = (l & 7) << 4;                        // (row&7)<<4
  const int aRow0 = (wm * 64 + fr) * 128;               // + m*2048 bytes
  const int swzc0 = (0 * 64 + (l >> 4) * 16) ^ rxor;    // K 0..31
  const int swzc1 = (1 * 64 + (l >> 4) * 16) ^ rxor;    // K 32..63

  // ---- B direct-global frag base: lane l -> row bn*128 + wn*64 + (l&15), k-chunk (l>>4)*8 ----
  const unsigned short* Bg = B + (size_t)(bn * 128 + wn * 64 + (l & 15)) * K_DIM + (l >> 4) * 8;

  // ping-pong fragment sets
  bf16x8 fa0[4][2], fa1[4][2];   // A frags [m][kc] from LDS
  bf16x8 bq0[4][2], bq1[4][2];   // B frags [n][kc] from global

#define LDA(FA, BUFC)                                                   \
  do {                                                                  \
    const char* Ab_ = lds + (BUFC) * ABUF;                              \
    _Pragma("unroll")                                                   \
    for (int m = 0; m < 4; ++m) {                                       \
      FA[m][0] = *(const bf16x8*)(Ab_ + aRow0 + m * 2048 + swzc0);      \
      FA[m][1] = *(const bf16x8*)(Ab_ + aRow0 + m * 2048 + swzc1);      \
    }                                                                   \
  } while (0)

#define LDB(BQ, T)                                                      \
  do {                                                                  \
    _Pragma("unroll")                                                   \
    for (int n = 0; n < 4; ++n) {                                       \
      BQ[n][0] = *(const bf16x8*)(Bg + n * 16 * K_DIM + (T) * BK + 0);  \
      BQ[n][1] = *(const bf16x8*)(Bg + n * 16 * K_DIM + (T) * BK + 32); \
    }                                                                   \
  } while (0)

#define MFMA32(FA, BQ, CNT)                                             \
  do {                                                                  \
    asm volatile("s_waitcnt lgkmcnt(" #CNT ")" ::: "memory");           \
    __builtin_amdgcn_sched_barrier(0);                                  \
    __builtin_amdgcn_s_setprio(1);                                      \
    _Pragma("unroll")                                                   \
    for (int kc = 0; kc < 2; ++kc)                                      \
      _Pragma("unroll")                                                 \
      for (int m = 0; m < 4; ++m)                                       \
        _Pragma("unroll")                                               \
        for (int n = 0; n < 4; ++n)                                     \
          acc[m][n] = __builtin_amdgcn_mfma_f32_16x16x32_bf16(FA[m][kc], BQ[n][kc], acc[m][n], 0, 0, 0); \
    __builtin_amdgcn_s_setprio(0);                                      \
    __builtin_amdgcn_sched_barrier(0);                                  \
  } while (0)

  // Body t (steady state):
  //  top: vmcnt(8) -> A-stage(t+1) landed (8 newest = Bfrag(t) regs, still fine
  //       to be in flight; compiler inserts the reg-dep wait before MFMA); BAR.
  //  LDA frags(t+1) [8 ds_reads]; STAGE_A(t+2) [4 GLD]; LDB frags(t+1) [8 loads]
  //  MFMA(t) with lgkm(8) (frags(t+1)'s reads outstanding).
#define BODY(T, BUF1, BUF2, FAc, FAn, BQc, BQn)                         \
  do {                                                                  \
    asm volatile("s_waitcnt vmcnt(8)" ::: "memory");                    \
    BAR();                                                              \
    LDA(FAn, BUF1);                                                     \
    STAGE_A(lds + (BUF2) * ABUF + w * 1024, Asrc0 + ((T) + 2) * BK);    \
    LDB(BQn, (T) + 1);                                                  \
    MFMA32(FAc, BQc, 8);                                                \
  } while (0)

  // ---- prologue: stage A(0), A(1); load B frags(0) ----
  STAGE_A(lds + 0 * ABUF + w * 1024, Asrc0 + 0 * BK);
  STAGE_A(lds + 1 * ABUF + w * 1024, Asrc0 + 1 * BK);
  LDB(bq0, 0);
  asm volatile("s_waitcnt vmcnt(12)" ::: "memory");   // A(0) landed (A(1)+B(0) in flight)
  BAR();
  LDA(fa0, 0);

  // ---- main loop: bodies 0..29, unroll x6 (buf %3, frag set %2) ----
  for (int t = 0; t < NT - 2; t += 6) {
    BODY(t + 0, 1, 2, fa0, fa1, bq0, bq1);
    BODY(t + 1, 2, 0, fa1, fa0, bq1, bq0);
    BODY(t + 2, 0, 1, fa0, fa1, bq0, bq1);
    BODY(t + 3, 1, 2, fa1, fa0, bq1, bq0);
    BODY(t + 4, 2, 0, fa0, fa1, bq0, bq1);
    BODY(t + 5, 0, 1, fa1, fa0, bq1, bq0);
  }

  // ---- body 30: no staging ----
  asm volatile("s_waitcnt vmcnt(8)" ::: "memory");    // A(31) landed (B(30) in flight)
  BAR();
  LDA(fa1, 1);           // frags(31) from buf 31%3 = 1
  LDB(bq1, 31);
  MFMA32(fa0, bq0, 8);
  // ---- body 31 ----
  MFMA32(fa1, bq1, 0);   // drain lgkm; compiler waits vmcnt for bq1

  // ---- epilogue: C/D layout col=lane&15, row=(lane>>4)*4+reg ----
  const int row0 = bm * 256 + wm * 64 + (l >> 4) * 4;
  const int col0 = bn * 128 + wn * 64 + (l & 15);
#pragma unroll
  for (int n = 0; n < 4; ++n) {
    float bv = bias[col0 + n * 16];
#pragma unroll
    for (int m = 0; m < 4; ++m) {
#pragma unroll
      for (int j = 0; j < 4; ++j) {
        C[(size_t)(row0 + m * 16 + j) * N_DIM + (col0 + n * 16)] = acc[m][n][j] + bv;
      }
    }
  }
#undef BODY
#undef MFMA32
#undef LDB
#undef LDA
}

// ---------------- fallback (ws too small): direct fp32 ----------------
__global__ __launch_bounds__(256) void fallback_kernel(const float* __restrict__ x,
                                                       const float* __restrict__ iv,
                                                       const float* __restrict__ b,
                                                       float* __restrict__ out) {
  int idx = blockIdx.x * 256 + threadIdx.x;
  int Bn = idx >> 11, o = idx & 2047;
  int f = o >> 4, t = o & 15;
  const float* xr = x + (size_t)Bn * 2048;
  float acc = 0.f;
  for (int g = 0; g < 128; ++g) {
    const float* pr = iv + (f * 128 + g) * 16;
    const float* xg = xr + g * 16;
#pragma unroll
    for (int s = 0; s < 16; ++s) acc += pr[s] * xg[(t - s) & 15];
  }
  out[idx] = acc + b[o];
}

extern "C" void kernel_launch(void* const* d_in, const int* in_sizes, int n_in,
                              void* d_out, int out_size, void* d_ws, size_t ws_size,
                              hipStream_t stream) {
  const float* x    = (const float*)d_in[0];
  const float* iv   = (const float*)d_in[1];
  const float* bias = (const float*)d_in[2];
  float* out = (float*)d_out;

  const size_t xb_bytes = (size_t)M_DIM * K_DIM * 2;
  const size_t w_bytes  = (size_t)N_DIM * K_DIM * 2;
  if (ws_size < xb_bytes + w_bytes) {
    fallback_kernel<<<(M_DIM * N_DIM) / 256, 256, 0, stream>>>(x, iv, bias, out);
    return;
  }

  unsigned short* xb = (unsigned short*)d_ws;
  unsigned short* W  = xb + (size_t)M_DIM * K_DIM;

  const int cvt_blocks = (M_DIM * K_DIM / 8) / 256;   // 4096
  const int bw_blocks  = (N_DIM * K_DIM / 8) / 256;   // 2048
  prep_kernel<<<cvt_blocks + bw_blocks, 256, 0, stream>>>(x, iv, xb, W);

  gemm_bias_kernel<<<(M_DIM / 256) * (N_DIM / 128), 512, 0, stream>>>(xb, W, bias, out);
}

// Round 7
// 76.668 us; speedup vs baseline: 1.3088x; 1.3033x over previous
//
#include <hip/hip_runtime.h>
#include <hip/hip_bf16.h>

// EnhancedBCMLayer: block-circulant matmul == dense GEMM
//   out = X (4096x2048 fp32) @ W^T (2048x2048) + b, fp32 out
//   W[f*16+t][g*16+u] = iv[f, g, (t-u)&15]
// GEMM: BM=256 x BN=128 x BK=64, grid 256 (1 block/CU), 8 waves (4M x 2N),
// per-wave 64x64, mfma_f32_16x16x32_bf16 (round-4 verified skeleton).
// A: fused fp32->bf16 staging — reg-stage (8x global_load_dwordx4), f2bf pack,
//    XOR-swizzled ds_write_b128 (T14 issue-early/write-late). No X pre-pass.
// B: global_load_lds from pre-built bf16 W (prep kernel builds W only).
// 3-buffer LDS, 2-tile prefetch, ping-pong frag sets, lgkm(8/12), T1+T2+T5.

#define M_DIM 4096
#define N_DIM 2048
#define K_DIM 2048
#define BK 64
#define NT (K_DIM / BK)   // 32 K-tiles
#define BUFSZ 49152       // 48 KB: A [256 rows][128B] + B [128 rows][128B] at +32768

typedef __attribute__((ext_vector_type(8))) short bf16x8;
typedef __attribute__((ext_vector_type(4))) float f32x4;

typedef const __attribute__((address_space(1))) void gvoid_t;
typedef __attribute__((address_space(3))) void lvoid_t;

#define FENCE asm volatile("" ::: "memory")
#define BAR()  do { FENCE; __builtin_amdgcn_s_barrier(); FENCE; } while (0)
#define GLD(src, dst) __builtin_amdgcn_global_load_lds((gvoid_t*)(src), (lvoid_t*)(dst), 16, 0, 0)

// B staging: 2 GLDs cover 128 rows x 64 k
#define STAGE_B(dst, src) (GLD((src) + 0 * 64 * K_DIM, (dst) + 0),     \
                           GLD((src) + 1 * 64 * K_DIM, (dst) + 8192))

// fp32 -> bf16 RNE
__device__ __forceinline__ unsigned int f2bf(float f) {
  unsigned int u = __float_as_uint(f);
  return (u + 0x7fffu + ((u >> 16) & 1u)) >> 16;
}

// ---------------- prologue kernel: expand iv -> dense bf16 W [N][K] ----------------
__global__ __launch_bounds__(256) void prep_kernel(const float* __restrict__ iv,
                                                   unsigned short* __restrict__ W) {
  int idx = blockIdx.x * 256 + threadIdx.x;   // one per 8 weights
  int o  = idx >> 8;             // W row 0..2047
  int i0 = (idx & 255) * 8;      // col start
  int f = o >> 4, t = o & 15;
  int g = i0 >> 4, u0 = i0 & 15;
  const float* row = iv + (f * 128 + g) * 16;
  unsigned int p[4];
#pragma unroll
  for (int j = 0; j < 4; ++j) {
    unsigned int lo = f2bf(row[(t - (u0 + 2 * j + 0)) & 15]);
    unsigned int hi = f2bf(row[(t - (u0 + 2 * j + 1)) & 15]);
    p[j] = lo | (hi << 16);
  }
  ((uint4*)W)[idx] = make_uint4(p[0], p[1], p[2], p[3]);
}

// ---------------- main GEMM ----------------
__global__ __launch_bounds__(512, 2) void gemm_bias_kernel(const float* __restrict__ X,
                                                           const unsigned short* __restrict__ B,
                                                           const float* __restrict__ bias,
                                                           float* __restrict__ C) {
  __shared__ char lds[3 * BUFSZ];   // 144 KB

  const int tid = threadIdx.x;
  const int l   = tid & 63;
  const int w   = tid >> 6;       // wave 0..7
  const int wm  = w >> 1;         // wave M 0..3 (64 rows each)
  const int wn  = w & 1;          // wave N 0..1 (64 cols each)

  // T1: XCD-aware bijective swizzle (grid=256, 256%8==0)
  const int orig = blockIdx.x;
  const int swz  = (orig & 7) * 32 + (orig >> 3);
  const int bm   = swz >> 4;      // 0..15
  const int bn   = swz & 15;      // 0..15

  f32x4 acc[4][4] = {};

  // ---- A reg-staging addresses ----
  // Lane covers rows j*64 + w*8 + (l>>3) (j=0..3), k-slot ks = l&7 (8 bf16).
  // fp32 source LINEAR; LDS write slot XOR-swizzled: slot = ks ^ (row&7),
  // row&7 == (l>>3)&7. Matches the ds_read swizzle (byte ^= (row&7)<<4).
  const int arow = w * 8 + (l >> 3);             // 0..63 (within j-group)
  const int ks   = l & 7;
  const float* Afp = X + (size_t)(bm * 256 + arow) * K_DIM + ks * 8;
  const int awbyte = arow * 128 + ((ks ^ ((l >> 3) & 7)) * 16);   // + j*8192 + buf base

  // ---- B staging (inverse-swizzled global source, linear LDS dest) ----
  const int srow  = w * 8 + (l >> 3);
  const int sslot = (l & 7) ^ ((l >> 3) & 7);
  const unsigned short* Bsrc0 = B + (size_t)(bn * 128 + srow) * K_DIM + sslot * 8;

  // ---- ds_read frag addresses (T2 swizzled) ----
  const int fr = l & 15;
  const int rxor = (l & 7) << 4;                        // (row&7)<<4
  const int aRow0 = (wm * 64 + fr) * 128;               // + m*2048 bytes
  const int bRow0 = (wn * 64 + fr) * 128;               // + n*2048 bytes
  const int swzcol0 = (0 * 64 + (l >> 4) * 16) ^ rxor;  // K 0..31
  const int swzcol1 = (1 * 64 + (l >> 4) * 16) ^ rxor;  // K 32..63

  // ping-pong fragment sets
  bf16x8 fa0[4], fb0[4], fa1[4], fb1[4];
  float4 av[4][2];   // staged fp32 A (one tile in flight)

#define LDA(SA, SB, BUF, SWZ)                                           \
  do {                                                                  \
    const char* Ab_ = lds + (BUF) * BUFSZ;                              \
    const char* Bb_ = Ab_ + 32768;                                      \
    _Pragma("unroll")                                                   \
    for (int m = 0; m < 4; ++m)                                         \
      SA[m] = *(const bf16x8*)(Ab_ + aRow0 + m * 2048 + (SWZ));         \
    _Pragma("unroll")                                                   \
    for (int n = 0; n < 4; ++n)                                         \
      SB[n] = *(const bf16x8*)(Bb_ + bRow0 + n * 2048 + (SWZ));         \
  } while (0)

#define ALOAD(T)                                                        \
  do {                                                                  \
    _Pragma("unroll")                                                   \
    for (int j = 0; j < 4; ++j) {                                       \
      av[j][0] = *(const float4*)(Afp + (size_t)j * 64 * K_DIM + (T) * BK + 0); \
      av[j][1] = *(const float4*)(Afp + (size_t)j * 64 * K_DIM + (T) * BK + 4); \
    }                                                                   \
  } while (0)

#define AWRITE(BUFC)                                                    \
  do {                                                                  \
    char* dst_ = lds + (BUFC) * BUFSZ;                                  \
    _Pragma("unroll")                                                   \
    for (int j = 0; j < 4; ++j) {                                       \
      uint4 u_;                                                         \
      u_.x = f2bf(av[j][0].x) | (f2bf(av[j][0].y) << 16);               \
      u_.y = f2bf(av[j][0].z) | (f2bf(av[j][0].w) << 16);               \
      u_.z = f2bf(av[j][1].x) | (f2bf(av[j][1].y) << 16);               \
      u_.w = f2bf(av[j][1].z) | (f2bf(av[j][1].w) << 16);               \
      *(uint4*)(dst_ + j * 8192 + awbyte) = u_;                         \
    }                                                                   \
  } while (0)

#define MM(SA, SB, CNT)                                                 \
  do {                                                                  \
    asm volatile("s_waitcnt lgkmcnt(" #CNT ")" ::: "memory");           \
    __builtin_amdgcn_sched_barrier(0);                                  \
    __builtin_amdgcn_s_setprio(1);                                      \
    _Pragma("unroll")                                                   \
    for (int m = 0; m < 4; ++m)                                         \
      _Pragma("unroll")                                                 \
      for (int n = 0; n < 4; ++n)                                       \
        acc[m][n] = __builtin_amdgcn_mfma_f32_16x16x32_bf16(SA[m], SB[n], acc[m][n], 0, 0, 0); \
    __builtin_amdgcn_s_setprio(0);                                      \
    __builtin_amdgcn_sched_barrier(0);                                  \
  } while (0)

  // Steady-state body t (buffers CUR=t%3, NXT=(t+1)%3, STG=(t+2)%3):
  // P0: LDA set1 (tile t, K 32..63) | ALOAD fp32 A(t+2) | MFMA set0 (lgkm 8)
  //     | pack+AWRITE A(t+2)->STG (compiler auto-vmcnts the reg deps)
  //     | vmcnt(0): B(t+1) GLD landed | BAR
  // P1: LDA set0 (tile t+1 from NXT) | STAGE_B(t+2)->STG | MFMA set1 (lgkm 12:
  //     4 writes + 8 new reads pending) | BAR
#define BODY(T, CUR, NXT, STG)                                          \
  do {                                                                  \
    LDA(fa1, fb1, CUR, swzcol1);                                        \
    ALOAD((T) + 2);                                                     \
    MM(fa0, fb0, 8);                                                    \
    AWRITE(STG);                                                        \
    asm volatile("s_waitcnt vmcnt(0)" ::: "memory");                    \
    BAR();                                                              \
    LDA(fa0, fb0, NXT, swzcol0);                                        \
    STAGE_B(lds + (STG) * BUFSZ + 32768 + w * 1024, Bsrc0 + ((T) + 2) * BK); \
    MM(fa1, fb1, 12);                                                   \
    BAR();                                                              \
  } while (0)

  // ---- prologue: stage tiles 0 and 1 (A via reg path, B via GLD) ----
  ALOAD(0);
  AWRITE(0);
  ALOAD(1);
  AWRITE(1);
  STAGE_B(lds + 0 * BUFSZ + 32768 + w * 1024, Bsrc0 + 0 * BK);
  STAGE_B(lds + 1 * BUFSZ + 32768 + w * 1024, Bsrc0 + 1 * BK);
  asm volatile("s_waitcnt vmcnt(0)" ::: "memory");    // B(0), B(1) landed
  asm volatile("s_waitcnt lgkmcnt(0)" ::: "memory");  // A writes visible
  BAR();
  LDA(fa0, fb0, 0, swzcol0);

  // ---- main loop: bodies 0..29, unroll x3 ----
  for (int t = 0; t < NT - 2; t += 3) {
    BODY(t + 0, 0, 1, 2);
    BODY(t + 1, 1, 2, 0);
    BODY(t + 2, 2, 0, 1);
  }

  // ---- tail: body 30 (buf 0), then body 31 (buf 1), no staging ----
  LDA(fa1, fb1, 0, swzcol1);
  MM(fa0, fb0, 8);              // lgkm(8) also drains body-29's 4 ds_writes
  asm volatile("s_waitcnt vmcnt(0)" ::: "memory");    // B(31) landed
  BAR();
  LDA(fa0, fb0, 1, swzcol0);
  MM(fa1, fb1, 8);
  LDA(fa1, fb1, 1, swzcol1);
  MM(fa0, fb0, 8);
  MM(fa1, fb1, 0);

  // ---- epilogue: C/D layout col=lane&15, row=(lane>>4)*4+reg ----
  const int row0 = bm * 256 + wm * 64 + (l >> 4) * 4;
  const int col0 = bn * 128 + wn * 64 + (l & 15);
#pragma unroll
  for (int n = 0; n < 4; ++n) {
    float bv = bias[col0 + n * 16];
#pragma unroll
    for (int m = 0; m < 4; ++m) {
#pragma unroll
      for (int j = 0; j < 4; ++j) {
        C[(size_t)(row0 + m * 16 + j) * N_DIM + (col0 + n * 16)] = acc[m][n][j] + bv;
      }
    }
  }
#undef BODY
#undef MM
#undef AWRITE
#undef ALOAD
#undef LDA
}

// ---------------- fallback (ws too small): direct fp32 ----------------
__global__ __launch_bounds__(256) void fallback_kernel(const float* __restrict__ x,
                                                       const float* __restrict__ iv,
                                                       const float* __restrict__ b,
                                                       float* __restrict__ out) {
  int idx = blockIdx.x * 256 + threadIdx.x;
  int Bn = idx >> 11, o = idx & 2047;
  int f = o >> 4, t = o & 15;
  const float* xr = x + (size_t)Bn * 2048;
  float acc = 0.f;
  for (int g = 0; g < 128; ++g) {
    const float* pr = iv + (f * 128 + g) * 16;
    const float* xg = xr + g * 16;
#pragma unroll
    for (int s = 0; s < 16; ++s) acc += pr[s] * xg[(t - s) & 15];
  }
  out[idx] = acc + b[o];
}

extern "C" void kernel_launch(void* const* d_in, const int* in_sizes, int n_in,
                              void* d_out, int out_size, void* d_ws, size_t ws_size,
                              hipStream_t stream) {
  const float* x    = (const float*)d_in[0];
  const float* iv   = (const float*)d_in[1];
  const float* bias = (const float*)d_in[2];
  float* out = (float*)d_out;

  const size_t w_bytes = (size_t)N_DIM * K_DIM * 2;   // 8 MB
  if (ws_size < w_bytes) {
    fallback_kernel<<<(M_DIM * N_DIM) / 256, 256, 0, stream>>>(x, iv, bias, out);
    return;
  }

  unsigned short* W = (unsigned short*)d_ws;

  prep_kernel<<<(N_DIM * K_DIM / 8) / 256, 256, 0, stream>>>(iv, W);   // 2048 blocks
  gemm_bias_kernel<<<(M_DIM / 256) * (N_DIM / 128), 512, 0, stream>>>(x, W, bias, out);
}